// Round 18
// baseline (178.619 us; speedup 1.0000x reference)
//
#include <hip/hip_runtime.h>
#include <math.h>

// EquiTritonModel: N=10000 nodes, E=160000 edges, D=32, H=16, NB=16.
// R17 -> R18: six theories on the 44us edge wall falsified; the untested
// constant is 224B/edge of scattered bucket WRITES (50MB @ ~1.1TB/s
// effective). Cut: phase2 un-fused to an edge-parallel kernel (R5/R9 shape,
// proven), so edge drops sbuf+hbuf+h1 (writes -29%, VALU -30%, -1 atomic);
// node drops its out-loop and writes Q/P to a tiny L2-resident zbuf that
// phase2 gathers (64B/edge random READS from 0.64MB = L2-cheap).

namespace {
constexpr int   NATOMS   = 100;
constexpr int   CAP      = 64;   // Poisson(16): P(deg>=64) ~ 1e-19
constexpr float PI_F     = 3.14159265358979323846f;
constexpr float INV4PI_F = 0.28209479177387814f;   // 1/sqrt(4*pi)
constexpr float SQRT3_F  = 1.7320508075688772f;
constexpr float CUT_F    = 6.0f;
constexpr float BASIS_C  = 2.3094010767585034f;    // sqrt(2/6)*sqrt(16)
constexpr float N0_F     = 0.17677669529663687f;   // 1/sqrt(32)
constexpr float K0_F = INV4PI_F * N0_F * 0.0625f;
constexpr float K1_F = SQRT3_F * INV4PI_F * N0_F * 0.0625f;
constexpr float P2SC = INV4PI_F * N0_F * (1.0f / 64.0f);
}

__device__ __forceinline__ float silu_fast(float x) {
  return x / (1.0f + __expf(-x));
}

__device__ __forceinline__ float block_reduce_sum(float v) {
  #pragma unroll
  for (int o = 32; o > 0; o >>= 1) v += __shfl_down(v, o, 64);
  __shared__ float ls[8];
  int lane = threadIdx.x & 63;
  int w    = threadIdx.x >> 6;
  if (lane == 0) ls[w] = v;
  __syncthreads();
  float s = 0.f;
  if (threadIdx.x == 0) {
    int nw = (blockDim.x + 63) >> 6;
    for (int i = 0; i < nw; ++i) s += ls[i];
  }
  return s;
}

// ---------------------------------------------------------------------------
// table_kernel: blocks [0,NATOMS) -> TI tables; block NATOMS -> G1T/G4T +
// out-zero; blocks > NATOMS zero dcur (N ints).
// ---------------------------------------------------------------------------
__global__ void table_kernel(const float* __restrict__ atom_emb,
                             const float* __restrict__ fc0_w2,
                             const float* __restrict__ fc1_w2,
                             const float* __restrict__ w_readout,
                             float* __restrict__ TI,
                             float* __restrict__ G1T, float* __restrict__ G4T,
                             int* __restrict__ dcur,
                             float* __restrict__ out,
                             int N) {
  int b = blockIdx.x;
  int tt = threadIdx.x;
  if (b < NATOMS) {
    int j = tt >> 4;
    int h = tt & 15;
    float s0 = 0.f, s1 = 0.f;
    #pragma unroll
    for (int d = 0; d < 32; ++d) {
      float x = atom_emb[b * 32 + d];
      s0 = fmaf(x, fc0_w2[j * 1024 + d * 16 + h], s0);
      s1 = fmaf(x, fc0_w2[j * 1024 + 512 + d * 16 + h], s1);
    }
    TI[b * 512 + j * 32 + 2 * h]     = s0;
    TI[b * 512 + j * 32 + 2 * h + 1] = s1;
  } else if (b == NATOMS) {
    int j = tt >> 4;
    int h = tt & 15;
    float g1 = 0.f, g4 = 0.f;
    #pragma unroll
    for (int k = 0; k < 16; ++k) {
      float r = w_readout[k];
      g1 = fmaf(fc1_w2[j * 1024 + h * 16 + k], r, g1);
      g4 = fmaf(fc1_w2[j * 1024 + 768 + h * 16 + k], r, g4);
    }
    G1T[h * 16 + j] = g1;
    G4T[h * 16 + j] = g4;
    if (tt == 0) *out = 0.f;
  } else {
    int idx = (b - NATOMS - 1) * 256 + tt;
    if (idx < N) dcur[idx] = 0;
  }
}

// ---------------------------------------------------------------------------
// edge_kernel: phased 2-edge pipeline (R14 minus h1/sbuf/hbuf/scur).
// 16 groups x 16 lanes; group handles edges b*32+g and b*32+16+g.
// Writes: evec[e] (phase2 input), ubuf[dslot], mbuf[dslot] (160 B/edge).
// ---------------------------------------------------------------------------
__global__ void __launch_bounds__(256)
edge_kernel(const int* __restrict__ ei,
            const float* __restrict__ coords,
            const int* __restrict__ an,
            const float* __restrict__ TI,
            const float* __restrict__ fc0_w1,
            int* __restrict__ dcur,
            float2* __restrict__ mbuf,
            float4* __restrict__ ubuf,
            float4* __restrict__ evec,
            int E) {
  int lane = threadIdx.x & 63;
  int g    = threadIdx.x >> 4;       // block group 0..15
  int t    = threadIdx.x & 15;
  int base = lane & 48;

  float w0c[16];
  #pragma unroll
  for (int k = 0; k < 16; ++k) w0c[k] = fc0_w1[k * 16 + t];

  const float angc = PI_F / CUT_F;
  int eA = blockIdx.x * 32 + g;
  int eB = eA + 16;
  bool vA = eA < E, vB = eB < E;
  int eAc = vA ? eA : 0, eBc = vB ? eB : 0;

  // ---- phase 1: all input loads ----
  int sA = ei[eAc], dA = ei[E + eAc];
  int sB = ei[eBc], dB = ei[E + eBc];
  float sxA = coords[3 * sA + 0], syA = coords[3 * sA + 1], szA = coords[3 * sA + 2];
  float dxA = coords[3 * dA + 0], dyA = coords[3 * dA + 1], dzA = coords[3 * dA + 2];
  float sxB = coords[3 * sB + 0], syB = coords[3 * sB + 1], szB = coords[3 * sB + 2];
  float dxB = coords[3 * dB + 0], dyB = coords[3 * dB + 1], dzB = coords[3 * dB + 2];
  int aA = an[sA], aB = an[sB];

  // ---- phase 2: geometry + early slot atomics ----
  float vxA = sxA - dxA, vyA = syA - dyA, vzA = szA - dzA;
  float vxB = sxB - dxB, vyB = syB - dyB, vzB = szB - dzB;
  float distA = sqrtf(vxA * vxA + vyA * vyA + vzA * vzA);
  float distB = sqrtf(vxB * vxB + vyB * vyB + vzB * vzB);
  float ivA = 1.0f / fmaxf(distA, 1e-9f);
  float ivB = 1.0f / fmaxf(distB, 1e-9f);
  float uxA = vxA * ivA, uyA = vyA * ivA, uzA = vzA * ivA;
  float uxB = vxB * ivB, uyB = vyB * ivB, uzB = vzB * ivB;
  float bcA = (distA < CUT_F) ? (BASIS_C * ivA) : 0.0f;
  float bcB = (distB < CUT_F) ? (BASIS_C * ivB) : 0.0f;

  int dsAv = 0, dsBv = 0;
  if (t == 0) {
    if (vA) {
      float4 rec = make_float4(uxA, uyA, uzA, distA);
      int p = atomicAdd(&dcur[dA], 1);
      dsAv = dA * CAP + min(p, CAP - 1);
      ubuf[dsAv] = rec;
      evec[eA] = rec;
    }
    if (vB) {
      float4 rec = make_float4(uxB, uyB, uzB, distB);
      int p = atomicAdd(&dcur[dB], 1);
      dsBv = dB * CAP + min(p, CAP - 1);
      ubuf[dsBv] = rec;
      evec[eB] = rec;
    }
  }

  // ---- phase 3: interleaved sine recurrences (h0 only) ----
  float angA = angc * distA, angB = angc * distB;
  float scA = __sinf(angA), twA = 2.0f * __cosf(angA), spA = 0.f;
  float scB = __sinf(angB), twB = 2.0f * __cosf(angB), spB = 0.f;
  float a0A = 0.f, a0B = 0.f;
  #pragma unroll
  for (int k = 0; k < 16; ++k) {
    a0A = fmaf(scA, w0c[k], a0A);
    a0B = fmaf(scB, w0c[k], a0B);
    float snA = fmaf(twA, scA, -spA); spA = scA; scA = snA;
    float snB = fmaf(twB, scB, -spB); spB = scB; scB = snB;
  }
  float h0A = silu_fast(a0A * bcA * 0.25f);
  float h0B = silu_fast(a0B * bcB * 0.25f);

  // slot broadcast (atomics issued long ago — latency covered)
  int dsA = __shfl(dsAv, base, 64);
  int dsB = __shfl(dsBv, base, 64);

  // ---- phase 4/5: interleaved TI loads + contraction ----
  const float2* tpA = (const float2*)(TI + aA * 512) + t;
  const float2* tpB = (const float2*)(TI + aB * 512) + t;
  float u0A = 0.f, u1A = 0.f, u0B = 0.f, u1B = 0.f;
  #pragma unroll
  for (int j = 0; j < 16; ++j) {
    float hjA = __shfl(h0A, base + j, 64);
    float hjB = __shfl(h0B, base + j, 64);
    float2 TA = tpA[j * 16];
    float2 TB = tpB[j * 16];
    u0A = fmaf(hjA, TA.x, u0A);
    u1A = fmaf(hjA, TA.y, u1A);
    u0B = fmaf(hjB, TB.x, u0B);
    u1B = fmaf(hjB, TB.y, u1B);
  }

  // ---- phase 6: bucket stores ----
  if (vA) mbuf[(size_t)dsA * 16 + t] = make_float2(K0_F * u0A, K1_F * u1A);
  if (vB) mbuf[(size_t)dsB * 16 + t] = make_float2(K0_F * u0B, K1_F * u1B);
}

// ---------------------------------------------------------------------------
// node_kernel: 256 thr = 4 waves = 4 nodes/block; 4 groups x 16 lanes.
// in-loop + butterfly + G-transform -> zbuf[node*64 + t*4 + g] (Q|Px|Py|Pz),
// + readout accumulation. No out-loop (phase2 is separate, edge-parallel).
// ---------------------------------------------------------------------------
__global__ void __launch_bounds__(256, 4)
node_kernel(const int* __restrict__ dcur,
            const float2* __restrict__ mbuf,
            const float4* __restrict__ ubuf,
            const float* __restrict__ G1T,
            const float* __restrict__ G4T,
            const float* __restrict__ w_readout,
            float* __restrict__ zbuf,
            float* __restrict__ out,
            int N) {
  __shared__ float ggs[512];          // [0:256)=G1T, [256:512)=G4T
  ggs[threadIdx.x]       = G1T[threadIdx.x];
  ggs[256 + threadIdx.x] = G4T[threadIdx.x];
  __syncthreads();

  int wave = threadIdx.x >> 6;
  int lane = threadIdx.x & 63;
  int g    = lane >> 4;
  int t    = lane & 15;
  int base = lane & 48;
  int node = blockIdx.x * 4 + wave;
  bool valid = node < N;

  float rr = w_readout[t];
  int cin = valid ? min(dcur[node], CAP) : 0;
  size_t nb = (size_t)(valid ? node : 0) * CAP;

  // ---- in-loop ----
  float a0 = 0.f, ax = 0.f, ay = 0.f, az = 0.f;
  for (int i = g; i < cin; i += 4) {
    float2 f  = mbuf[(nb + i) * 16 + t];
    float4 uu = ubuf[nb + i];            // group-uniform broadcast
    a0 += f.x;
    ax = fmaf(f.y, uu.x, ax);
    ay = fmaf(f.y, uu.y, ay);
    az = fmaf(f.y, uu.z, az);
  }
  a0 += __shfl_xor(a0, 16, 64); a0 += __shfl_xor(a0, 32, 64);
  ax += __shfl_xor(ax, 16, 64); ax += __shfl_xor(ax, 32, 64);
  ay += __shfl_xor(ay, 16, 64); ay += __shfl_xor(ay, 32, 64);
  az += __shfl_xor(az, 16, 64); az += __shfl_xor(az, 32, 64);

  // ---- G-transform ----
  float srcv = (g == 0) ? a0 : ((g == 1) ? ax : (g == 2) ? ay : az);
  int tofs = (g == 0) ? 0 : 256;
  float o = 0.f;
  #pragma unroll
  for (int h = 0; h < 16; ++h) {
    float vh = __shfl(srcv, base + h, 64);
    o = fmaf(ggs[tofs + h * 16 + t], vh, o);
  }
  // zbuf[node][t][g]: phase2 lane t reads float4 (Q,Px,Py,Pz)
  if (valid) zbuf[(size_t)node * 64 + t * 4 + g] = o;

  // readout: 0.25 * z0_t * r_t (group 0 lanes hold z0 = a0)
  float p = (valid && g == 0) ? a0 * rr : 0.f;
  float tot = block_reduce_sum(p);
  if (threadIdx.x == 0) atomicAdd(out, tot * 0.25f);
}

// ---------------------------------------------------------------------------
// phase2_kernel: one 16-lane group per edge (grid-stride). Lane t owns j=t.
// Streams ei/evec; random float4 gather from L2-resident zbuf (0.64 MB).
// c_e = P2SC * sum_j h1_j * (Q_j + P_j . u)
// ---------------------------------------------------------------------------
__global__ void __launch_bounds__(256, 4)
phase2_kernel(const int* __restrict__ ei,
              const float4* __restrict__ evec,
              const float* __restrict__ fc1_w1,
              const float* __restrict__ zbuf,
              float* __restrict__ out,
              int E) {
  int t = threadIdx.x & 15;
  float w1c[16];
  #pragma unroll
  for (int k = 0; k < 16; ++k) w1c[k] = fc1_w1[k * 16 + t];

  int gid = (blockIdx.x * blockDim.x + threadIdx.x) >> 4;
  int ngroups = (gridDim.x * blockDim.x) >> 4;
  const float angc = PI_F / CUT_F;

  float c = 0.f;
  for (int e = gid; e < E; e += ngroups) {
    int s = ei[e];
    float4 ev = evec[e];
    float dist = ev.w;
    float bc = (dist < CUT_F) ? (BASIS_C / fmaxf(dist, 1e-9f)) : 0.0f;

    float ang = angc * dist;
    float sc = __sinf(ang);
    float tw = 2.0f * __cosf(ang);
    float sp = 0.f, acc = 0.f;
    #pragma unroll
    for (int k = 0; k < 16; ++k) {
      acc = fmaf(sc, w1c[k], acc);
      float sn = fmaf(tw, sc, -sp);
      sp = sc; sc = sn;
    }
    float h1t = silu_fast(acc * bc * 0.25f);

    float4 z = ((const float4*)(zbuf + (size_t)s * 64))[t];
    c = fmaf(h1t, fmaf(z.y, ev.x, fmaf(z.z, ev.y, fmaf(z.w, ev.z, z.x))), c);
  }
  c *= P2SC;
  float tot = block_reduce_sum(c);
  if (threadIdx.x == 0) atomicAdd(out, tot);
}

extern "C" void kernel_launch(void* const* d_in, const int* in_sizes, int n_in,
                              void* d_out, int out_size, void* d_ws, size_t ws_size,
                              hipStream_t stream) {
  const int*   an        = (const int*)d_in[0];
  const float* coords    = (const float*)d_in[1];
  const int*   ei        = (const int*)d_in[2];
  const float* atom_emb  = (const float*)d_in[3];
  const float* fc0_w1    = (const float*)d_in[4];
  const float* fc0_w2    = (const float*)d_in[5];
  const float* fc1_w1    = (const float*)d_in[6];
  const float* fc1_w2    = (const float*)d_in[7];
  const float* w_readout = (const float*)d_in[8];

  int N = in_sizes[0];
  int E = in_sizes[2] / 2;
  size_t slots = (size_t)N * CAP;

  // ws layout (16B-aligned arrays first). ~95 MB of ~256 MB ws.
  float4* ubuf = (float4*)d_ws;                 // N*CAP        (10 MB)
  float4* evec = ubuf + slots;                  // E            (2.6 MB)
  float2* mbuf = (float2*)(evec + E);           // N*CAP*16     (82 MB)
  float*  zbuf = (float*)(mbuf + slots * 16);   // N*64         (2.6 MB)
  float*  TI   = zbuf + (size_t)N * 64;         // 100*512
  float*  G1T  = TI + NATOMS * 512;             // 256
  float*  G4T  = G1T + 256;                     // 256
  int*    dcur = (int*)(G4T + 256);             // N
  float*  out = (float*)d_out;

  int blk = 256;
  int zgrid = (N + blk - 1) / blk;
  table_kernel<<<NATOMS + 1 + zgrid, blk, 0, stream>>>(
      atom_emb, fc0_w2, fc1_w2, w_readout, TI, G1T, G4T, dcur, out, N);

  edge_kernel<<<(E + 31) / 32, blk, 0, stream>>>(
      ei, coords, an, TI, fc0_w1, dcur, mbuf, ubuf, evec, E);

  node_kernel<<<(N + 3) / 4, blk, 0, stream>>>(
      dcur, mbuf, ubuf, G1T, G4T, w_readout, zbuf, out, N);

  phase2_kernel<<<2048, blk, 0, stream>>>(ei, evec, fc1_w1, zbuf, out, E);
}

// Round 19
// 161.054 us; speedup vs baseline: 1.1091x; 1.1091x over previous
//
#include <hip/hip_runtime.h>
#include <math.h>

// EquiTritonModel: N=10000 nodes, E=160000 edges, D=32, H=16, NB=16.
// R18 -> R19: write-volume theory falsified (WRITE 50->32MB, time flat).
// All ~44us variants share the dependent chain ei->coords->an->TI at the
// head of group-per-edge work (~600-900cyc serial L2 round-trips, 2-4
// waves/SIMD of cover). Split on the R14 base:
//  - geom_kernel: LANE-per-edge (64 independent chains/wave = full MLP):
//    gathers + geometry + slot atomics + ubuf/sbuf scatter + contiguous
//    erec/eaux records.
//  - comp_kernel: group-per-edge, purely CONTIGUOUS inputs (erec/eaux);
//    slots arrive in every lane (no slot shfls, no t==0 predication);
//    twin recurrences + TI contraction + mbuf/hbuf scatter stores.
//  - node_kernel: R14's fused (in-loop + G + out-loop phase2 + readout).

namespace {
constexpr int   NATOMS   = 100;
constexpr int   CAP      = 64;   // Poisson(16): P(deg>=64) ~ 1e-19
constexpr float PI_F     = 3.14159265358979323846f;
constexpr float INV4PI_F = 0.28209479177387814f;   // 1/sqrt(4*pi)
constexpr float SQRT3_F  = 1.7320508075688772f;
constexpr float CUT_F    = 6.0f;
constexpr float BASIS_C  = 2.3094010767585034f;    // sqrt(2/6)*sqrt(16)
constexpr float N0_F     = 0.17677669529663687f;   // 1/sqrt(32)
constexpr float K0_F = INV4PI_F * N0_F * 0.0625f;
constexpr float K1_F = SQRT3_F * INV4PI_F * N0_F * 0.0625f;
constexpr float P2SC = INV4PI_F * N0_F * (1.0f / 64.0f);
}

__device__ __forceinline__ float silu_fast(float x) {
  return x / (1.0f + __expf(-x));
}

__device__ __forceinline__ float block_reduce_sum(float v) {
  #pragma unroll
  for (int o = 32; o > 0; o >>= 1) v += __shfl_down(v, o, 64);
  __shared__ float ls[8];
  int lane = threadIdx.x & 63;
  int w    = threadIdx.x >> 6;
  if (lane == 0) ls[w] = v;
  __syncthreads();
  float s = 0.f;
  if (threadIdx.x == 0) {
    int nw = (blockDim.x + 63) >> 6;
    for (int i = 0; i < nw; ++i) s += ls[i];
  }
  return s;
}

// ---------------------------------------------------------------------------
// table_kernel: blocks [0,NATOMS) -> TI tables; block NATOMS -> G1T/G4T +
// out-zero; blocks > NATOMS zero dcur/scur (2N ints).
// ---------------------------------------------------------------------------
__global__ void table_kernel(const float* __restrict__ atom_emb,
                             const float* __restrict__ fc0_w2,
                             const float* __restrict__ fc1_w2,
                             const float* __restrict__ w_readout,
                             float* __restrict__ TI,
                             float* __restrict__ G1T, float* __restrict__ G4T,
                             int* __restrict__ dcur,   // dcur..dcur+2N zeroed
                             float* __restrict__ out,
                             int N2) {
  int b = blockIdx.x;
  int tt = threadIdx.x;
  if (b < NATOMS) {
    int j = tt >> 4;
    int h = tt & 15;
    float s0 = 0.f, s1 = 0.f;
    #pragma unroll
    for (int d = 0; d < 32; ++d) {
      float x = atom_emb[b * 32 + d];
      s0 = fmaf(x, fc0_w2[j * 1024 + d * 16 + h], s0);
      s1 = fmaf(x, fc0_w2[j * 1024 + 512 + d * 16 + h], s1);
    }
    TI[b * 512 + j * 32 + 2 * h]     = s0;
    TI[b * 512 + j * 32 + 2 * h + 1] = s1;
  } else if (b == NATOMS) {
    int j = tt >> 4;
    int h = tt & 15;
    float g1 = 0.f, g4 = 0.f;
    #pragma unroll
    for (int k = 0; k < 16; ++k) {
      float r = w_readout[k];
      g1 = fmaf(fc1_w2[j * 1024 + h * 16 + k], r, g1);
      g4 = fmaf(fc1_w2[j * 1024 + 768 + h * 16 + k], r, g4);
    }
    G1T[h * 16 + j] = g1;
    G4T[h * 16 + j] = g4;
    if (tt == 0) *out = 0.f;
  } else {
    int idx = (b - NATOMS - 1) * 256 + tt;
    if (idx < N2) dcur[idx] = 0;
  }
}

// ---------------------------------------------------------------------------
// geom_kernel: LANE-per-edge. 64 independent gather chains per wave.
// Writes contiguous erec/eaux + scattered ubuf/sbuf; 2 atomics/edge.
// ---------------------------------------------------------------------------
__global__ void __launch_bounds__(256)
geom_kernel(const int* __restrict__ ei,
            const float* __restrict__ coords,
            const int* __restrict__ an,
            int* __restrict__ dcur, int* __restrict__ scur,
            float4* __restrict__ ubuf,
            float4* __restrict__ sbuf,
            float4* __restrict__ erec,
            int4* __restrict__ eaux,
            int E) {
  int e = blockIdx.x * blockDim.x + threadIdx.x;
  if (e >= E) return;
  int s = ei[e];
  int d = ei[E + e];
  float vx = coords[3 * s + 0] - coords[3 * d + 0];
  float vy = coords[3 * s + 1] - coords[3 * d + 1];
  float vz = coords[3 * s + 2] - coords[3 * d + 2];
  float dist = sqrtf(vx * vx + vy * vy + vz * vz);
  float inv  = 1.0f / fmaxf(dist, 1e-9f);
  float4 rec = make_float4(vx * inv, vy * inv, vz * inv, dist);

  int dp = atomicAdd(&dcur[d], 1);
  int sp = atomicAdd(&scur[s], 1);
  int ds = d * CAP + min(dp, CAP - 1);
  int ss = s * CAP + min(sp, CAP - 1);
  ubuf[ds] = rec;
  sbuf[ss] = rec;
  erec[e] = rec;
  eaux[e] = make_int4(an[s], ds, ss, 0);
}

// ---------------------------------------------------------------------------
// comp_kernel: group-per-edge, 2 edges/group, purely contiguous inputs.
// 16 groups x 16 lanes; group handles edges b*32+g and b*32+16+g.
// Twin sine recurrences (h0+h1), TI contraction, scattered mbuf/hbuf stores.
// ---------------------------------------------------------------------------
__global__ void __launch_bounds__(256)
comp_kernel(const float4* __restrict__ erec,
            const int4* __restrict__ eaux,
            const float* __restrict__ TI,
            const float* __restrict__ fc0_w1,
            const float* __restrict__ fc1_w1,
            float2* __restrict__ mbuf,
            float* __restrict__ hbuf,
            int E) {
  int lane = threadIdx.x & 63;
  int g    = threadIdx.x >> 4;       // block group 0..15
  int t    = threadIdx.x & 15;
  int base = lane & 48;

  float w0c[16], w1c[16];
  #pragma unroll
  for (int k = 0; k < 16; ++k) {
    w0c[k] = fc0_w1[k * 16 + t];
    w1c[k] = fc1_w1[k * 16 + t];
  }

  const float angc = PI_F / CUT_F;
  int eA = blockIdx.x * 32 + g;
  int eB = eA + 16;
  bool vA = eA < E, vB = eB < E;
  int eAc = vA ? eA : 0, eBc = vB ? eB : 0;

  // ---- contiguous input loads (no indirection) ----
  float4 rA = erec[eAc];
  float4 rB = erec[eBc];
  int4   xA = eaux[eAc];
  int4   xB = eaux[eBc];
  float distA = rA.w, distB = rB.w;
  float bcA = (distA < CUT_F) ? (BASIS_C / fmaxf(distA, 1e-9f)) : 0.0f;
  float bcB = (distB < CUT_F) ? (BASIS_C / fmaxf(distB, 1e-9f)) : 0.0f;

  // ---- twin interleaved sine recurrences ----
  float angA = angc * distA, angB = angc * distB;
  float scA = __sinf(angA), twA = 2.0f * __cosf(angA), spA = 0.f;
  float scB = __sinf(angB), twB = 2.0f * __cosf(angB), spB = 0.f;
  float a0A = 0.f, a1A = 0.f, a0B = 0.f, a1B = 0.f;
  #pragma unroll
  for (int k = 0; k < 16; ++k) {
    a0A = fmaf(scA, w0c[k], a0A);
    a1A = fmaf(scA, w1c[k], a1A);
    a0B = fmaf(scB, w0c[k], a0B);
    a1B = fmaf(scB, w1c[k], a1B);
    float snA = fmaf(twA, scA, -spA); spA = scA; scA = snA;
    float snB = fmaf(twB, scB, -spB); spB = scB; scB = snB;
  }
  float h0A = silu_fast(a0A * bcA * 0.25f);
  float h1A = silu_fast(a1A * bcA * 0.25f);
  float h0B = silu_fast(a0B * bcB * 0.25f);
  float h1B = silu_fast(a1B * bcB * 0.25f);

  // ---- TI contraction (interleaved A/B) ----
  const float2* tpA = (const float2*)(TI + xA.x * 512) + t;
  const float2* tpB = (const float2*)(TI + xB.x * 512) + t;
  float u0A = 0.f, u1A = 0.f, u0B = 0.f, u1B = 0.f;
  #pragma unroll
  for (int j = 0; j < 16; ++j) {
    float hjA = __shfl(h0A, base + j, 64);
    float hjB = __shfl(h0B, base + j, 64);
    float2 TA = tpA[j * 16];
    float2 TB = tpB[j * 16];
    u0A = fmaf(hjA, TA.x, u0A);
    u1A = fmaf(hjA, TA.y, u1A);
    u0B = fmaf(hjB, TB.x, u0B);
    u1B = fmaf(hjB, TB.y, u1B);
  }

  // ---- bucket stores (slots already in every lane) ----
  if (vA) {
    hbuf[(size_t)xA.z * 16 + t] = h1A;
    mbuf[(size_t)xA.y * 16 + t] = make_float2(K0_F * u0A, K1_F * u1A);
  }
  if (vB) {
    hbuf[(size_t)xB.z * 16 + t] = h1B;
    mbuf[(size_t)xB.y * 16 + t] = make_float2(K0_F * u0B, K1_F * u1B);
  }
}

// ---------------------------------------------------------------------------
// node_kernel (fused z-build + phase2 + readout): 256 thr = 4 waves = 4
// nodes/block; 4 groups x 16 lanes. Both loops stream slim records. (R14)
// ---------------------------------------------------------------------------
__global__ void __launch_bounds__(256, 4)
node_kernel(const int* __restrict__ dcur,
            const int* __restrict__ scur,
            const float2* __restrict__ mbuf,
            const float4* __restrict__ ubuf,
            const float4* __restrict__ sbuf,
            const float* __restrict__ hbuf,
            const float* __restrict__ G1T,
            const float* __restrict__ G4T,
            const float* __restrict__ w_readout,
            float* __restrict__ out,
            int N) {
  __shared__ float ggs[512];          // [0:256)=G1T, [256:512)=G4T
  ggs[threadIdx.x]       = G1T[threadIdx.x];
  ggs[256 + threadIdx.x] = G4T[threadIdx.x];
  __syncthreads();

  int wave = threadIdx.x >> 6;
  int lane = threadIdx.x & 63;
  int g    = lane >> 4;
  int t    = lane & 15;
  int base = lane & 48;
  int node = blockIdx.x * 4 + wave;
  bool valid = node < N;

  float rr = w_readout[t];
  int cin  = valid ? min(dcur[node], CAP) : 0;
  int cout = valid ? min(scur[node], CAP) : 0;
  size_t nb = (size_t)(valid ? node : 0) * CAP;

  // ---- 1) in-loop ----
  float a0 = 0.f, ax = 0.f, ay = 0.f, az = 0.f;
  for (int i = g; i < cin; i += 4) {
    float2 f  = mbuf[(nb + i) * 16 + t];
    float4 uu = ubuf[nb + i];            // group-uniform broadcast
    a0 += f.x;
    ax = fmaf(f.y, uu.x, ax);
    ay = fmaf(f.y, uu.y, ay);
    az = fmaf(f.y, uu.z, az);
  }
  a0 += __shfl_xor(a0, 16, 64); a0 += __shfl_xor(a0, 32, 64);
  ax += __shfl_xor(ax, 16, 64); ax += __shfl_xor(ax, 32, 64);
  ay += __shfl_xor(ay, 16, 64); ay += __shfl_xor(ay, 32, 64);
  az += __shfl_xor(az, 16, 64); az += __shfl_xor(az, 32, 64);

  // ---- 2) G-transform ----
  float srcv = (g == 0) ? a0 : ((g == 1) ? ax : (g == 2) ? ay : az);
  int tofs = (g == 0) ? 0 : 256;
  float o = 0.f;
  #pragma unroll
  for (int h = 0; h < 16; ++h) {
    float vh = __shfl(srcv, base + h, 64);
    o = fmaf(ggs[tofs + h * 16 + t], vh, o);
  }
  // distribute: every lane gets Q_t, Px_t, Py_t, Pz_t
  float Qt  = __shfl(o, t, 64);
  float Pxt = __shfl(o, 16 + t, 64);
  float Pyt = __shfl(o, 32 + t, 64);
  float Pzt = __shfl(o, 48 + t, 64);

  // ---- 3) out-loop (fused phase 2; h1 precomputed in comp_kernel) ----
  float c = 0.f;
  for (int i = g; i < cout; i += 4) {
    float h1 = hbuf[(nb + i) * 16 + t];  // coalesced 64B/group
    float4 uu = sbuf[nb + i];            // group-uniform broadcast
    c = fmaf(h1, fmaf(Pxt, uu.x, fmaf(Pyt, uu.y, fmaf(Pzt, uu.z, Qt))), c);
  }
  c *= P2SC;
  // readout term: 0.25 * z0_t * r_t (group 0 lanes hold z0 = a0)
  if (valid && g == 0) c = fmaf(a0 * rr, 0.25f, c);
  if (!valid) c = 0.f;

  float tot = block_reduce_sum(c);
  if (threadIdx.x == 0) atomicAdd(out, tot);
}

extern "C" void kernel_launch(void* const* d_in, const int* in_sizes, int n_in,
                              void* d_out, int out_size, void* d_ws, size_t ws_size,
                              hipStream_t stream) {
  const int*   an        = (const int*)d_in[0];
  const float* coords    = (const float*)d_in[1];
  const int*   ei        = (const int*)d_in[2];
  const float* atom_emb  = (const float*)d_in[3];
  const float* fc0_w1    = (const float*)d_in[4];
  const float* fc0_w2    = (const float*)d_in[5];
  const float* fc1_w1    = (const float*)d_in[6];
  const float* fc1_w2    = (const float*)d_in[7];
  const float* w_readout = (const float*)d_in[8];

  int N = in_sizes[0];
  int E = in_sizes[2] / 2;
  size_t slots = (size_t)N * CAP;

  // ws layout (16B-aligned arrays first). ~148 MB of ~256 MB ws.
  float4* ubuf = (float4*)d_ws;                 // N*CAP        (10 MB)
  float4* sbuf = ubuf + slots;                  // N*CAP        (10 MB)
  float4* erec = sbuf + slots;                  // E            (2.6 MB)
  int4*   eaux = (int4*)(erec + E);             // E            (2.6 MB)
  float2* mbuf = (float2*)(eaux + E);           // N*CAP*16     (82 MB)
  float*  hbuf = (float*)(mbuf + slots * 16);   // N*CAP*16     (41 MB)
  float*  TI   = hbuf + slots * 16;             // 100*512
  float*  G1T  = TI + NATOMS * 512;             // 256
  float*  G4T  = G1T + 256;                     // 256
  int*    dcur = (int*)(G4T + 256);             // N
  int*    scur = dcur + N;                      // N (contiguous after dcur)
  float*  out = (float*)d_out;

  int blk = 256;
  int zgrid = (2 * N + blk - 1) / blk;
  table_kernel<<<NATOMS + 1 + zgrid, blk, 0, stream>>>(
      atom_emb, fc0_w2, fc1_w2, w_readout, TI, G1T, G4T, dcur, out, 2 * N);

  geom_kernel<<<(E + blk - 1) / blk, blk, 0, stream>>>(
      ei, coords, an, dcur, scur, ubuf, sbuf, erec, eaux, E);

  comp_kernel<<<(E + 31) / 32, blk, 0, stream>>>(
      erec, eaux, TI, fc0_w1, fc1_w1, mbuf, hbuf, E);

  node_kernel<<<(N + 3) / 4, blk, 0, stream>>>(
      dcur, scur, mbuf, ubuf, sbuf, hbuf, G1T, G4T, w_readout, out, N);
}